// Round 3
// baseline (421.825 us; speedup 1.0000x reference)
//
#include <hip/hip_runtime.h>
#include <hip/hip_bf16.h>
#include <stdint.h>

// Problem constants (fixed by setup_inputs)
#define NN 10000
#define EE 160000
#define BB 2
#define TT 12
#define FF 16
#define HG 32
#define HH 64
#define PP 4
#define BT (BB*TT)   // 24
#define MM (BB*NN)   // 20000

typedef _Float16 half8 __attribute__((ext_vector_type(8)));
typedef float f32x4 __attribute__((ext_vector_type(4)));

__device__ __forceinline__ float sigm(float x) { return 1.0f / (1.0f + __expf(-x)); }
__device__ __forceinline__ float tanhfast(float x) { return 1.0f - 2.0f / (__expf(2.0f*x) + 1.0f); }

// ---------------- GCN: degree histogram ----------------
__global__ void k_count(const int* __restrict__ eidx, int* __restrict__ cnt) {
  int e = blockIdx.x * 256 + threadIdx.x;
  if (e < EE) atomicAdd(&cnt[eidx[EE + e]], 1);
}

// single-block scan: offsets (exclusive) + dinv = rsqrt(deg) with self-loop (+1)
__global__ void k_scan(const int* __restrict__ cnt, int* __restrict__ off,
                       float* __restrict__ dinv) {
  __shared__ int partial[1024];
  int tid = threadIdx.x;
  const int CH = 10;  // 1024*10 >= 10000
  int base = tid * CH;
  int s = 0;
  for (int i = 0; i < CH; ++i) {
    int idx = base + i;
    if (idx < NN) s += cnt[idx];
  }
  partial[tid] = s;
  __syncthreads();
  for (int d = 1; d < 1024; d <<= 1) {
    int v = (tid >= d) ? partial[tid - d] : 0;
    __syncthreads();
    partial[tid] += v;
    __syncthreads();
  }
  int run = (tid == 0) ? 0 : partial[tid - 1];
  for (int i = 0; i < CH; ++i) {
    int idx = base + i;
    if (idx < NN) {
      off[idx] = run;
      int cv = cnt[idx];
      run += cv;
      dinv[idx] = rsqrtf((float)cv + 1.0f);
    }
  }
  if (tid == 1023) off[NN] = run;  // == EE
}

__global__ void k_fill(const int* __restrict__ eidx, const int* __restrict__ off,
                       int* __restrict__ fill, int* __restrict__ csr) {
  int e = blockIdx.x * 256 + threadIdx.x;
  if (e < EE) {
    int d = eidx[EE + e];
    int pos = atomicAdd(&fill[d], 1);
    csr[off[d] + pos] = eidx[e];
  }
}

// ---------------- xw = era5 @ gcn_w  (fp16 out, [BT][N][Hg]) ----------------
__global__ __launch_bounds__(256) void k_xw(const float* __restrict__ era5,
                                            const float* __restrict__ gw,
                                            _Float16* __restrict__ xw) {
  __shared__ float wsm[FF * HG];
  int tid = threadIdx.x;
  wsm[tid] = gw[tid];
  wsm[tid + 256] = gw[tid + 256];
  __syncthreads();
  int idx = blockIdx.x * 256 + tid;
  int c = idx & 31;
  int rest = idx >> 5;
  int n = rest % NN;
  int bt = rest / NN;
  const float* xr = era5 + ((size_t)bt * NN + n) * FF;
  float acc = 0.f;
#pragma unroll
  for (int f = 0; f < FF; ++f) acc += xr[f] * wsm[f * HG + c];
  xw[idx] = (_Float16)acc;
}

// -------- GCN aggregate (gather form), writes LSTM layout [b*N+n][T][Hg] fp16 --------
__global__ __launch_bounds__(256) void k_gather(const _Float16* __restrict__ xw,
                                                const int* __restrict__ off,
                                                const int* __restrict__ csr,
                                                const float* __restrict__ dinv,
                                                const float* __restrict__ gb,
                                                _Float16* __restrict__ gout) {
  int idx = blockIdx.x * 256 + threadIdx.x;
  int c = idx & 31;
  int rest = idx >> 5;
  int dst = rest % NN;
  int bt = rest / NN;
  int b = bt / TT, t = bt % TT;
  const _Float16* xwb = xw + (size_t)bt * (NN * HG);
  int s0 = off[dst], s1 = off[dst + 1];
  float acc = 0.f;
  for (int i = s0; i < s1; ++i) {
    int s = csr[i];
    acc += (float)xwb[s * HG + c] * dinv[s];
  }
  float dd = dinv[dst];
  acc = (acc + (float)xwb[dst * HG + c] * dd) * dd + gb[c];
  gout[(((size_t)b * NN + dst) * TT + t) * HG + c] = (_Float16)acc;
}

// ---------------- fused dual LSTM (fp16 MFMA, fp32 state) ----------------
// Block: 256 thr (4 waves), 16 sequences. Wave w owns hidden units [16w,16w+16):
// N-tiles {w, w+4, w+8, w+12} = i/f/g/o gate columns for those units.
// LSTM1 (lstm=0): x = gout rows (Hg=32 wide), A0 loaded straight from global fp16.
// LSTM2 (lstm=1): x is scalar zeta; folded into accumulator init (no MFMA).
// h round-trips through double-buffered LDS -> ONE barrier per timestep.
__global__ __launch_bounds__(256) void k_lstm(
    const _Float16* __restrict__ gout, const float* __restrict__ zeta,
    const float* __restrict__ w_ih1, const float* __restrict__ w_hh1,
    const float* __restrict__ b_ih1, const float* __restrict__ b_hh1,
    const float* __restrict__ w_ih2, const float* __restrict__ w_hh2,
    const float* __restrict__ b_ih2, const float* __restrict__ b_hh2,
    float* __restrict__ hout) {
  const int lstm = blockIdx.y;
  const int m0 = blockIdx.x * 16;
  const int tid = threadIdx.x;
  const int wave = tid >> 6;
  const int lane = tid & 63;
  const int col = lane & 15;   // A-row m / B-col n / D-col
  const int quad = lane >> 4;  // A/B k-chunk selector; D rows quad*4 + r

  const float* w_hh = lstm ? w_hh2 : w_hh1;
  const float* bi = lstm ? b_ih2 : b_ih1;
  const float* bh = lstm ? b_hh2 : b_hh1;

  half8 Bx[4];      // x-chunk weights (lstm0 only), k in [0,32)
  half8 Bh[4][2];   // h-chunk weights, k in [32,96)
  float wx[4];      // lstm1: scalar w_ih2 column
  float bias[4];
#pragma unroll
  for (int g = 0; g < 4; ++g) {
    int ncol = 16 * (wave + 4 * g) + col;  // gate index 0..255
    bias[g] = bi[ncol] + bh[ncol];
    if (lstm == 0) {
#pragma unroll
      for (int j = 0; j < 8; ++j) Bx[g][j] = (_Float16)w_ih1[ncol * HG + quad * 8 + j];
    } else {
      wx[g] = w_ih2[ncol];
    }
#pragma unroll
    for (int c = 0; c < 2; ++c) {
#pragma unroll
      for (int j = 0; j < 8; ++j)
        Bh[g][c][j] = (_Float16)w_hh[ncol * HH + c * 32 + quad * 8 + j];
    }
  }

  // h double buffer: 16 rows x 72 halves (stride 72: 16B-aligned b128 reads)
  __shared__ __align__(16) _Float16 hbuf[2][16 * 72];
  __shared__ float zbuf[2][16];
  for (int i = tid; i < 16 * 72; i += 256) hbuf[1][i] = (_Float16)0.0f;

  float cst[4] = {0.f, 0.f, 0.f, 0.f};
  float hreg[4] = {0.f, 0.f, 0.f, 0.f};

  for (int t = 0; t < TT; ++t) {
    const int rp = (t + 1) & 1;  // buffer holding h(t-1)
    if (t > 0) {
#pragma unroll
      for (int r = 0; r < 4; ++r)
        hbuf[rp][(quad * 4 + r) * 72 + 16 * wave + col] = (_Float16)hreg[r];
    }
    if (lstm == 1 && tid < 16) {
      int m = m0 + tid;
      int b = m / NN, n = m % NN;
      zbuf[t & 1][tid] = zeta[((size_t)b * TT + t) * NN + n];
    }
    __syncthreads();

    f32x4 acc[4];
    if (lstm == 0) {
      half8 A0 = *(const half8*)(gout + ((size_t)(m0 + col) * TT + t) * HG + quad * 8);
#pragma unroll
      for (int g = 0; g < 4; ++g) {
        f32x4 a; a[0] = bias[g]; a[1] = bias[g]; a[2] = bias[g]; a[3] = bias[g];
        acc[g] = __builtin_amdgcn_mfma_f32_16x16x32_f16(A0, Bx[g], a, 0, 0, 0);
      }
    } else {
#pragma unroll
      for (int g = 0; g < 4; ++g) {
#pragma unroll
        for (int r = 0; r < 4; ++r)
          acc[g][r] = bias[g] + wx[g] * zbuf[t & 1][quad * 4 + r];
      }
    }
    const half8 A1 = *(const half8*)(&hbuf[rp][col * 72 + quad * 8]);
    const half8 A2 = *(const half8*)(&hbuf[rp][col * 72 + 32 + quad * 8]);
#pragma unroll
    for (int g = 0; g < 4; ++g) {
      acc[g] = __builtin_amdgcn_mfma_f32_16x16x32_f16(A1, Bh[g][0], acc[g], 0, 0, 0);
      acc[g] = __builtin_amdgcn_mfma_f32_16x16x32_f16(A2, Bh[g][1], acc[g], 0, 0, 0);
    }
#pragma unroll
    for (int r = 0; r < 4; ++r) {
      float ig = sigm(acc[0][r]);
      float fg = sigm(acc[1][r]);
      float gg = tanhfast(acc[2][r]);
      float og = sigm(acc[3][r]);
      cst[r] = fg * cst[r] + ig * gg;
      hreg[r] = og * tanhfast(cst[r]);
    }
    // no second barrier: next iteration writes the OTHER hbuf/zbuf parity
  }
#pragma unroll
  for (int r = 0; r < 4; ++r) {
    int s = quad * 4 + r;
    hout[((size_t)lstm * MM + m0 + s) * HH + 16 * wave + col] = hreg[r];
  }
}

// ---------------- FC + transpose to [B][P][N] (fp32 out) ----------------
__global__ __launch_bounds__(256) void k_fc(const float* __restrict__ hout,
                                            const float* __restrict__ fw,
                                            const float* __restrict__ fb,
                                            float* __restrict__ out) {
  __shared__ float wf[PP * 2 * HH];  // 512
  __shared__ float bf[PP];
  int tid = threadIdx.x;
  wf[tid] = fw[tid];
  wf[tid + 256] = fw[tid + 256];
  if (tid < PP) bf[tid] = fb[tid];
  __syncthreads();
  int m = blockIdx.x * 256 + tid;
  if (m >= MM) return;
  const float* h1 = hout + (size_t)m * HH;
  const float* h2 = hout + (size_t)(MM + m) * HH;
  float acc[PP];
#pragma unroll
  for (int p = 0; p < PP; ++p) acc[p] = bf[p];
  for (int k = 0; k < HH; ++k) {
    float v = h1[k];
#pragma unroll
    for (int p = 0; p < PP; ++p) acc[p] += v * wf[p * 128 + k];
  }
  for (int k = 0; k < HH; ++k) {
    float v = h2[k];
#pragma unroll
    for (int p = 0; p < PP; ++p) acc[p] += v * wf[p * 128 + 64 + k];
  }
  int b = m / NN, n = m % NN;
#pragma unroll
  for (int p = 0; p < PP; ++p)
    out[((size_t)(b * PP + p)) * NN + n] = acc[p];
}

extern "C" void kernel_launch(void* const* d_in, const int* in_sizes, int n_in,
                              void* d_out, int out_size, void* d_ws, size_t ws_size,
                              hipStream_t stream) {
  (void)in_sizes; (void)n_in; (void)out_size; (void)ws_size;
  const float* era5  = (const float*)d_in[0];
  const float* zeta  = (const float*)d_in[1];
  const int*   eidx  = (const int*)d_in[2];
  const float* gcn_w = (const float*)d_in[3];
  const float* gcn_b = (const float*)d_in[4];
  const float* w_ih1 = (const float*)d_in[5];
  const float* w_hh1 = (const float*)d_in[6];
  const float* b_ih1 = (const float*)d_in[7];
  const float* b_hh1 = (const float*)d_in[8];
  const float* w_ih2 = (const float*)d_in[9];
  const float* w_hh2 = (const float*)d_in[10];
  const float* b_ih2 = (const float*)d_in[11];
  const float* b_hh2 = (const float*)d_in[12];
  const float* fc_w  = (const float*)d_in[13];
  const float* fc_b  = (const float*)d_in[14];
  float* out = (float*)d_out;

  // Compact workspace: peak usage < 32 MB.
  char* ws = (char*)d_ws;
  float*     dinv   = (float*)(ws);                    //  40 KB
  int*       cnt    = (int*)(ws + (64 << 10));
  int*       off    = (int*)(ws + (128 << 10));
  int*       fill   = (int*)(ws + (192 << 10));
  int*       csr    = (int*)(ws + (256 << 10));        // 640 KB -> ends at 896 KB
  _Float16*  xw     = (_Float16*)(ws + (1ull << 20));  // 15.36 MB -> ends 16.36 MB
  _Float16*  gout   = (_Float16*)(ws + 17301504ull);   // @16.5 MB, 15.36 MB -> ends 31.2 MB
  float*     hout   = (float*)(ws + (1ull << 20));     // aliases dead xw: 10.24 MB

  hipMemsetAsync(ws + (64 << 10), 0, (192 << 10), stream);  // cnt, off, fill
  k_count<<<EE / 256, 256, 0, stream>>>(eidx, cnt);
  k_scan<<<1, 1024, 0, stream>>>(cnt, off, dinv);
  k_fill<<<EE / 256, 256, 0, stream>>>(eidx, off, fill, csr);
  k_xw<<<(BT * NN * HG) / 256, 256, 0, stream>>>(era5, gcn_w, xw);
  k_gather<<<(BT * NN * HG) / 256, 256, 0, stream>>>(xw, off, csr, dinv, gcn_b, gout);
  k_lstm<<<dim3(MM / 16, 2), 256, 0, stream>>>(gout, zeta, w_ih1, w_hh1, b_ih1, b_hh1,
                                               w_ih2, w_hh2, b_ih2, b_hh2, hout);
  k_fc<<<(MM + 255) / 256, 256, 0, stream>>>(hout, fc_w, fc_b, out);
}

// Round 4
// 291.083 us; speedup vs baseline: 1.4492x; 1.4492x over previous
//
#include <hip/hip_runtime.h>
#include <hip/hip_bf16.h>
#include <stdint.h>

// Problem constants (fixed by setup_inputs)
#define NN 10000
#define EE 160000
#define BB 2
#define TT 12
#define FF 16
#define HG 32
#define HH 64
#define PP 4
#define BT (BB*TT)   // 24
#define MM (BB*NN)   // 20000

typedef _Float16 half8 __attribute__((ext_vector_type(8)));
typedef _Float16 h2 __attribute__((ext_vector_type(2)));
typedef float f32x4 __attribute__((ext_vector_type(4)));

union UP { uint32_t u; h2 h; };

__device__ __forceinline__ float sigm(float x) { return 1.0f / (1.0f + __expf(-x)); }
__device__ __forceinline__ float tanhfast(float x) { return 1.0f - 2.0f / (__expf(2.0f*x) + 1.0f); }

// ---------------- GCN: degree histogram ----------------
__global__ void k_count(const int* __restrict__ eidx, int* __restrict__ cnt) {
  int e = blockIdx.x * 256 + threadIdx.x;
  if (e < EE) atomicAdd(&cnt[eidx[EE + e]], 1);
}

// single-block scan: offsets (exclusive) + dinv = rsqrt(deg) with self-loop (+1)
__global__ void k_scan(const int* __restrict__ cnt, int* __restrict__ off,
                       float* __restrict__ dinv) {
  __shared__ int partial[1024];
  int tid = threadIdx.x;
  const int CH = 10;  // 1024*10 >= 10000
  int base = tid * CH;
  int s = 0;
  for (int i = 0; i < CH; ++i) {
    int idx = base + i;
    if (idx < NN) s += cnt[idx];
  }
  partial[tid] = s;
  __syncthreads();
  for (int d = 1; d < 1024; d <<= 1) {
    int v = (tid >= d) ? partial[tid - d] : 0;
    __syncthreads();
    partial[tid] += v;
    __syncthreads();
  }
  int run = (tid == 0) ? 0 : partial[tid - 1];
  for (int i = 0; i < CH; ++i) {
    int idx = base + i;
    if (idx < NN) {
      off[idx] = run;
      int cv = cnt[idx];
      run += cv;
      dinv[idx] = rsqrtf((float)cv + 1.0f);
    }
  }
  if (tid == 1023) off[NN] = run;  // == EE
}

__global__ void k_fill(const int* __restrict__ eidx, const int* __restrict__ off,
                       int* __restrict__ fill, int* __restrict__ csr) {
  int e = blockIdx.x * 256 + threadIdx.x;
  if (e < EE) {
    int d = eidx[EE + e];
    int pos = atomicAdd(&fill[d], 1);
    csr[off[d] + pos] = eidx[e];
  }
}

// ------- xw = era5 @ gcn_w, TRANSPOSED layout [N][BT][HG] fp16 -------
__global__ __launch_bounds__(256) void k_xw(const float* __restrict__ era5,
                                            const float* __restrict__ gw,
                                            _Float16* __restrict__ xw) {
  __shared__ float wsm[FF * HG];
  int tid = threadIdx.x;
  wsm[tid] = gw[tid];
  wsm[tid + 256] = gw[tid + 256];
  __syncthreads();
  int idx = blockIdx.x * 256 + tid;
  int c = idx & 31;
  int rest = idx >> 5;
  int n = rest % NN;
  int bt = rest / NN;
  const float* xr = era5 + ((size_t)bt * NN + n) * FF;
  float acc = 0.f;
#pragma unroll
  for (int f = 0; f < FF; ++f) acc += xr[f] * wsm[f * HG + c];
  xw[((size_t)n * BT + bt) * HG + c] = (_Float16)acc;
}

// -------- GCN aggregate: ONE WAVE PER DST, cooperative row gather --------
// xw: [N][BT][HG] fp16 viewed as dwords (384/row). Wave lanes cooperatively
// load each neighbor row as 3x uint2 (512B/instr coalesced). Lane owns 12
// accumulators: halfwords v = 256k + 4*lane + j (k<3, j<4) of the 768-value
// (bt,c) space. Output gout stays [B*N][T][HG] fp16 (k_lstm layout).
__global__ __launch_bounds__(256) void k_gather(const uint32_t* __restrict__ xw,
                                                const int* __restrict__ off,
                                                const int* __restrict__ csr,
                                                const float* __restrict__ dinv,
                                                const float* __restrict__ gb,
                                                uint32_t* __restrict__ gout) {
  const int dst = (blockIdx.x * 256 + threadIdx.x) >> 6;
  const int lane = threadIdx.x & 63;
  if (dst >= NN) return;
  const int s0 = off[dst], s1 = off[dst + 1];
  const int cnt = s1 - s0;

  float accs[12];
#pragma unroll
  for (int i = 0; i < 12; ++i) accs[i] = 0.f;

  for (int base = 0; base < cnt; base += 64) {
    int mine = base + lane;
    int sv = 0; float dvv = 0.f;
    if (mine < cnt) { sv = csr[s0 + mine]; dvv = dinv[sv]; }
    int lim = min(64, cnt - base);
    for (int j = 0; j < lim; ++j) {
      int sj = __shfl(sv, j);
      float dj = __shfl(dvv, j);
      const uint32_t* row = xw + (size_t)sj * 384;
#pragma unroll
      for (int k = 0; k < 3; ++k) {
        uint2 d = *(const uint2*)(row + 2 * (lane + 64 * k));
        UP a, b; a.u = d.x; b.u = d.y;
        accs[4 * k + 0] += (float)a.h[0] * dj;
        accs[4 * k + 1] += (float)a.h[1] * dj;
        accs[4 * k + 2] += (float)b.h[0] * dj;
        accs[4 * k + 3] += (float)b.h[1] * dj;
      }
    }
  }
  // self loop + final scale + bias
  const float ddst = dinv[dst];
  const uint32_t* srow = xw + (size_t)dst * 384;
  const f32x4 gb4 = *(const f32x4*)(gb + ((4 * lane) & 31));
#pragma unroll
  for (int k = 0; k < 3; ++k) {
    uint2 d = *(const uint2*)(srow + 2 * (lane + 64 * k));
    UP a, b; a.u = d.x; b.u = d.y;
    accs[4 * k + 0] = (accs[4 * k + 0] + (float)a.h[0] * ddst) * ddst + gb4[0];
    accs[4 * k + 1] = (accs[4 * k + 1] + (float)a.h[1] * ddst) * ddst + gb4[1];
    accs[4 * k + 2] = (accs[4 * k + 2] + (float)b.h[0] * ddst) * ddst + gb4[2];
    accs[4 * k + 3] = (accs[4 * k + 3] + (float)b.h[1] * ddst) * ddst + gb4[3];
  }
  // write: v0 = 256k + 4*lane; b = (v0>=384); gout row (b*NN+dst), dword off (v0-384b)/2
#pragma unroll
  for (int k = 0; k < 3; ++k) {
    int v0 = 256 * k + 4 * lane;
    int bb = (v0 >= 384) ? 1 : 0;
    UP a, b;
    a.h[0] = (_Float16)accs[4 * k + 0]; a.h[1] = (_Float16)accs[4 * k + 1];
    b.h[0] = (_Float16)accs[4 * k + 2]; b.h[1] = (_Float16)accs[4 * k + 3];
    uint2 d; d.x = a.u; d.y = b.u;
    *(uint2*)(gout + ((size_t)(bb * NN + dst)) * 192 + ((v0 - 384 * bb) >> 1)) = d;
  }
}

// ---------------- fused dual LSTM (fp16 MFMA, fp32 state) ----------------
__global__ __launch_bounds__(256) void k_lstm(
    const _Float16* __restrict__ gout, const float* __restrict__ zeta,
    const float* __restrict__ w_ih1, const float* __restrict__ w_hh1,
    const float* __restrict__ b_ih1, const float* __restrict__ b_hh1,
    const float* __restrict__ w_ih2, const float* __restrict__ w_hh2,
    const float* __restrict__ b_ih2, const float* __restrict__ b_hh2,
    float* __restrict__ hout) {
  const int lstm = blockIdx.y;
  const int m0 = blockIdx.x * 16;
  const int tid = threadIdx.x;
  const int wave = tid >> 6;
  const int lane = tid & 63;
  const int col = lane & 15;   // A-row m / B-col n / D-col
  const int quad = lane >> 4;  // A/B k-chunk selector; D rows quad*4 + r

  const float* w_hh = lstm ? w_hh2 : w_hh1;
  const float* bi = lstm ? b_ih2 : b_ih1;
  const float* bh = lstm ? b_hh2 : b_hh1;

  half8 Bx[4];      // x-chunk weights (lstm0 only), k in [0,32)
  half8 Bh[4][2];   // h-chunk weights, k in [32,96)
  float wx[4];      // lstm1: scalar w_ih2 column
  float bias[4];
#pragma unroll
  for (int g = 0; g < 4; ++g) {
    int ncol = 16 * (wave + 4 * g) + col;  // gate index 0..255
    bias[g] = bi[ncol] + bh[ncol];
    if (lstm == 0) {
#pragma unroll
      for (int j = 0; j < 8; ++j) Bx[g][j] = (_Float16)w_ih1[ncol * HG + quad * 8 + j];
    } else {
      wx[g] = w_ih2[ncol];
    }
#pragma unroll
    for (int c = 0; c < 2; ++c) {
#pragma unroll
      for (int j = 0; j < 8; ++j)
        Bh[g][c][j] = (_Float16)w_hh[ncol * HH + c * 32 + quad * 8 + j];
    }
  }

  // h double buffer: 16 rows x 72 halves (stride 72: 16B-aligned b128 reads)
  __shared__ __align__(16) _Float16 hbuf[2][16 * 72];
  __shared__ float zbuf[2][16];
  for (int i = tid; i < 16 * 72; i += 256) hbuf[1][i] = (_Float16)0.0f;

  float cst[4] = {0.f, 0.f, 0.f, 0.f};
  float hreg[4] = {0.f, 0.f, 0.f, 0.f};

  for (int t = 0; t < TT; ++t) {
    const int rp = (t + 1) & 1;  // buffer holding h(t-1)
    if (t > 0) {
#pragma unroll
      for (int r = 0; r < 4; ++r)
        hbuf[rp][(quad * 4 + r) * 72 + 16 * wave + col] = (_Float16)hreg[r];
    }
    if (lstm == 1 && tid < 16) {
      int m = m0 + tid;
      int b = m / NN, n = m % NN;
      zbuf[t & 1][tid] = zeta[((size_t)b * TT + t) * NN + n];
    }
    __syncthreads();

    f32x4 acc[4];
    if (lstm == 0) {
      half8 A0 = *(const half8*)(gout + ((size_t)(m0 + col) * TT + t) * HG + quad * 8);
#pragma unroll
      for (int g = 0; g < 4; ++g) {
        f32x4 a; a[0] = bias[g]; a[1] = bias[g]; a[2] = bias[g]; a[3] = bias[g];
        acc[g] = __builtin_amdgcn_mfma_f32_16x16x32_f16(A0, Bx[g], a, 0, 0, 0);
      }
    } else {
#pragma unroll
      for (int g = 0; g < 4; ++g) {
#pragma unroll
        for (int r = 0; r < 4; ++r)
          acc[g][r] = bias[g] + wx[g] * zbuf[t & 1][quad * 4 + r];
      }
    }
    const half8 A1 = *(const half8*)(&hbuf[rp][col * 72 + quad * 8]);
    const half8 A2 = *(const half8*)(&hbuf[rp][col * 72 + 32 + quad * 8]);
#pragma unroll
    for (int g = 0; g < 4; ++g) {
      acc[g] = __builtin_amdgcn_mfma_f32_16x16x32_f16(A1, Bh[g][0], acc[g], 0, 0, 0);
      acc[g] = __builtin_amdgcn_mfma_f32_16x16x32_f16(A2, Bh[g][1], acc[g], 0, 0, 0);
    }
#pragma unroll
    for (int r = 0; r < 4; ++r) {
      float ig = sigm(acc[0][r]);
      float fg = sigm(acc[1][r]);
      float gg = tanhfast(acc[2][r]);
      float og = sigm(acc[3][r]);
      cst[r] = fg * cst[r] + ig * gg;
      hreg[r] = og * tanhfast(cst[r]);
    }
    // no second barrier: next iteration writes the OTHER hbuf/zbuf parity
  }
#pragma unroll
  for (int r = 0; r < 4; ++r) {
    int s = quad * 4 + r;
    hout[((size_t)lstm * MM + m0 + s) * HH + 16 * wave + col] = hreg[r];
  }
}

// ---------------- FC + transpose to [B][P][N] (fp32 out) ----------------
__global__ __launch_bounds__(256) void k_fc(const float* __restrict__ hout,
                                            const float* __restrict__ fw,
                                            const float* __restrict__ fb,
                                            float* __restrict__ out) {
  __shared__ float wf[PP * 2 * HH];  // 512
  __shared__ float bf[PP];
  int tid = threadIdx.x;
  wf[tid] = fw[tid];
  wf[tid + 256] = fw[tid + 256];
  if (tid < PP) bf[tid] = fb[tid];
  __syncthreads();
  int m = blockIdx.x * 256 + tid;
  if (m >= MM) return;
  const float* h1 = hout + (size_t)m * HH;
  const float* h2 = hout + (size_t)(MM + m) * HH;
  float acc[PP];
#pragma unroll
  for (int p = 0; p < PP; ++p) acc[p] = bf[p];
  for (int k = 0; k < HH; ++k) {
    float v = h1[k];
#pragma unroll
    for (int p = 0; p < PP; ++p) acc[p] += v * wf[p * 128 + k];
  }
  for (int k = 0; k < HH; ++k) {
    float v = h2[k];
#pragma unroll
    for (int p = 0; p < PP; ++p) acc[p] += v * wf[p * 128 + 64 + k];
  }
  int b = m / NN, n = m % NN;
#pragma unroll
  for (int p = 0; p < PP; ++p)
    out[((size_t)(b * PP + p)) * NN + n] = acc[p];
}

extern "C" void kernel_launch(void* const* d_in, const int* in_sizes, int n_in,
                              void* d_out, int out_size, void* d_ws, size_t ws_size,
                              hipStream_t stream) {
  (void)in_sizes; (void)n_in; (void)out_size; (void)ws_size;
  const float* era5  = (const float*)d_in[0];
  const float* zeta  = (const float*)d_in[1];
  const int*   eidx  = (const int*)d_in[2];
  const float* gcn_w = (const float*)d_in[3];
  const float* gcn_b = (const float*)d_in[4];
  const float* w_ih1 = (const float*)d_in[5];
  const float* w_hh1 = (const float*)d_in[6];
  const float* b_ih1 = (const float*)d_in[7];
  const float* b_hh1 = (const float*)d_in[8];
  const float* w_ih2 = (const float*)d_in[9];
  const float* w_hh2 = (const float*)d_in[10];
  const float* b_ih2 = (const float*)d_in[11];
  const float* b_hh2 = (const float*)d_in[12];
  const float* fc_w  = (const float*)d_in[13];
  const float* fc_b  = (const float*)d_in[14];
  float* out = (float*)d_out;

  // Compact workspace: peak usage < 32 MB.
  char* ws = (char*)d_ws;
  float*     dinv   = (float*)(ws);                    //  40 KB
  int*       cnt    = (int*)(ws + (64 << 10));
  int*       off    = (int*)(ws + (128 << 10));
  int*       fill   = (int*)(ws + (192 << 10));
  int*       csr    = (int*)(ws + (256 << 10));        // 640 KB -> ends at 896 KB
  _Float16*  xw     = (_Float16*)(ws + (1ull << 20));  // [N][24][32] 15.36 MB
  _Float16*  gout   = (_Float16*)(ws + 17301504ull);   // @16.5 MB, 15.36 MB
  float*     hout   = (float*)(ws + (1ull << 20));     // aliases dead xw: 10.24 MB

  hipMemsetAsync(ws + (64 << 10), 0, (192 << 10), stream);  // cnt, off, fill
  k_count<<<EE / 256, 256, 0, stream>>>(eidx, cnt);
  k_scan<<<1, 1024, 0, stream>>>(cnt, off, dinv);
  k_fill<<<EE / 256, 256, 0, stream>>>(eidx, off, fill, csr);
  k_xw<<<(BT * NN * HG) / 256, 256, 0, stream>>>(era5, gcn_w, xw);
  k_gather<<<(NN + 3) / 4, 256, 0, stream>>>((const uint32_t*)xw, off, csr, dinv,
                                             gcn_b, (uint32_t*)gout);
  k_lstm<<<dim3(MM / 16, 2), 256, 0, stream>>>(gout, zeta, w_ih1, w_hh1, b_ih1, b_hh1,
                                               w_ih2, w_hh2, b_ih2, b_hh2, hout);
  k_fc<<<(MM + 255) / 256, 256, 0, stream>>>(hout, fc_w, fc_b, out);
}

// Round 5
// 258.953 us; speedup vs baseline: 1.6290x; 1.1241x over previous
//
#include <hip/hip_runtime.h>
#include <hip/hip_bf16.h>
#include <stdint.h>

// Problem constants (fixed by setup_inputs)
#define NN 10000
#define EE 160000
#define BB 2
#define TT 12
#define FF 16
#define HG 32
#define HH 64
#define PP 4
#define BT (BB*TT)   // 24
#define MM (BB*NN)   // 20000

typedef _Float16 half8 __attribute__((ext_vector_type(8)));
typedef _Float16 h2 __attribute__((ext_vector_type(2)));
typedef float f32x4 __attribute__((ext_vector_type(4)));

union UP { uint32_t u; h2 h; };

__device__ __forceinline__ float fast_rcp(float x) { return __builtin_amdgcn_rcpf(x); }
// raw v_rcp (1 ulp): avoids the ~9-instr IEEE divide sequence
__device__ __forceinline__ float sigm(float x) { return fast_rcp(1.0f + __expf(-x)); }
__device__ __forceinline__ float tanhfast(float x) {
  return 1.0f - 2.0f * fast_rcp(__expf(2.0f * x) + 1.0f);
}

// ---------------- GCN: degree histogram ----------------
__global__ void k_count(const int* __restrict__ eidx, int* __restrict__ cnt) {
  int e = blockIdx.x * 256 + threadIdx.x;
  if (e < EE) atomicAdd(&cnt[eidx[EE + e]], 1);
}

// single-block scan: offsets (exclusive) + dinv = rsqrt(deg) with self-loop (+1)
__global__ void k_scan(const int* __restrict__ cnt, int* __restrict__ off,
                       float* __restrict__ dinv) {
  __shared__ int partial[1024];
  int tid = threadIdx.x;
  const int CH = 10;  // 1024*10 >= 10000
  int base = tid * CH;
  int s = 0;
  for (int i = 0; i < CH; ++i) {
    int idx = base + i;
    if (idx < NN) s += cnt[idx];
  }
  partial[tid] = s;
  __syncthreads();
  for (int d = 1; d < 1024; d <<= 1) {
    int v = (tid >= d) ? partial[tid - d] : 0;
    __syncthreads();
    partial[tid] += v;
    __syncthreads();
  }
  int run = (tid == 0) ? 0 : partial[tid - 1];
  for (int i = 0; i < CH; ++i) {
    int idx = base + i;
    if (idx < NN) {
      off[idx] = run;
      int cv = cnt[idx];
      run += cv;
      dinv[idx] = rsqrtf((float)cv + 1.0f);
    }
  }
  if (tid == 1023) off[NN] = run;  // == EE
}

__global__ void k_fill(const int* __restrict__ eidx, const int* __restrict__ off,
                       int* __restrict__ fill, int* __restrict__ csr) {
  int e = blockIdx.x * 256 + threadIdx.x;
  if (e < EE) {
    int d = eidx[EE + e];
    int pos = atomicAdd(&fill[d], 1);
    csr[off[d] + pos] = eidx[e];
  }
}

// ------- xw = era5 @ gcn_w, TRANSPOSED layout [N][BT][HG] fp16 -------
__global__ __launch_bounds__(256) void k_xw(const float* __restrict__ era5,
                                            const float* __restrict__ gw,
                                            _Float16* __restrict__ xw) {
  __shared__ float wsm[FF * HG];
  int tid = threadIdx.x;
  wsm[tid] = gw[tid];
  wsm[tid + 256] = gw[tid + 256];
  __syncthreads();
  int idx = blockIdx.x * 256 + tid;
  int c = idx & 31;
  int rest = idx >> 5;
  int n = rest % NN;
  int bt = rest / NN;
  const float* xr = era5 + ((size_t)bt * NN + n) * FF;
  float acc = 0.f;
#pragma unroll
  for (int f = 0; f < FF; ++f) acc += xr[f] * wsm[f * HG + c];
  xw[((size_t)n * BT + bt) * HG + c] = (_Float16)acc;
}

// -------- GCN aggregate: ONE WAVE PER DST, cooperative row gather --------
__global__ __launch_bounds__(256) void k_gather(const uint32_t* __restrict__ xw,
                                                const int* __restrict__ off,
                                                const int* __restrict__ csr,
                                                const float* __restrict__ dinv,
                                                const float* __restrict__ gb,
                                                uint32_t* __restrict__ gout) {
  const int dst = (blockIdx.x * 256 + threadIdx.x) >> 6;
  const int lane = threadIdx.x & 63;
  if (dst >= NN) return;
  const int s0 = off[dst], s1 = off[dst + 1];
  const int cnt = s1 - s0;

  float accs[12];
#pragma unroll
  for (int i = 0; i < 12; ++i) accs[i] = 0.f;

  for (int base = 0; base < cnt; base += 64) {
    int mine = base + lane;
    int sv = 0; float dvv = 0.f;
    if (mine < cnt) { sv = csr[s0 + mine]; dvv = dinv[sv]; }
    int lim = min(64, cnt - base);
    for (int j = 0; j < lim; ++j) {
      int sj = __shfl(sv, j);
      float dj = __shfl(dvv, j);
      const uint32_t* row = xw + (size_t)sj * 384;
#pragma unroll
      for (int k = 0; k < 3; ++k) {
        uint2 d = *(const uint2*)(row + 2 * (lane + 64 * k));
        UP a, b; a.u = d.x; b.u = d.y;
        accs[4 * k + 0] += (float)a.h[0] * dj;
        accs[4 * k + 1] += (float)a.h[1] * dj;
        accs[4 * k + 2] += (float)b.h[0] * dj;
        accs[4 * k + 3] += (float)b.h[1] * dj;
      }
    }
  }
  // self loop + final scale + bias
  const float ddst = dinv[dst];
  const uint32_t* srow = xw + (size_t)dst * 384;
  const f32x4 gb4 = *(const f32x4*)(gb + ((4 * lane) & 31));
#pragma unroll
  for (int k = 0; k < 3; ++k) {
    uint2 d = *(const uint2*)(srow + 2 * (lane + 64 * k));
    UP a, b; a.u = d.x; b.u = d.y;
    accs[4 * k + 0] = (accs[4 * k + 0] + (float)a.h[0] * ddst) * ddst + gb4[0];
    accs[4 * k + 1] = (accs[4 * k + 1] + (float)a.h[1] * ddst) * ddst + gb4[1];
    accs[4 * k + 2] = (accs[4 * k + 2] + (float)b.h[0] * ddst) * ddst + gb4[2];
    accs[4 * k + 3] = (accs[4 * k + 3] + (float)b.h[1] * ddst) * ddst + gb4[3];
  }
#pragma unroll
  for (int k = 0; k < 3; ++k) {
    int v0 = 256 * k + 4 * lane;
    int bb = (v0 >= 384) ? 1 : 0;
    UP a, b;
    a.h[0] = (_Float16)accs[4 * k + 0]; a.h[1] = (_Float16)accs[4 * k + 1];
    b.h[0] = (_Float16)accs[4 * k + 2]; b.h[1] = (_Float16)accs[4 * k + 3];
    uint2 d; d.x = a.u; d.y = b.u;
    *(uint2*)(gout + ((size_t)(bb * NN + dst)) * 192 + ((v0 - 384 * bb) >> 1)) = d;
  }
}

// ---------------- fused dual LSTM (fp16 MFMA, fp32 state) ----------------
// A0 (x-input) for all 12 timesteps prefetched to registers; zeta prefetched
// to LDS. One barrier per timestep (h double-buffer).
__global__ __launch_bounds__(256) void k_lstm(
    const _Float16* __restrict__ gout, const float* __restrict__ zeta,
    const float* __restrict__ w_ih1, const float* __restrict__ w_hh1,
    const float* __restrict__ b_ih1, const float* __restrict__ b_hh1,
    const float* __restrict__ w_ih2, const float* __restrict__ w_hh2,
    const float* __restrict__ b_ih2, const float* __restrict__ b_hh2,
    float* __restrict__ hout) {
  const int lstm = blockIdx.y;
  const int m0 = blockIdx.x * 16;
  const int tid = threadIdx.x;
  const int wave = tid >> 6;
  const int lane = tid & 63;
  const int col = lane & 15;   // A-row m / B-col n / D-col
  const int quad = lane >> 4;  // A/B k-chunk selector; D rows quad*4 + r

  const float* w_hh = lstm ? w_hh2 : w_hh1;
  const float* bi = lstm ? b_ih2 : b_ih1;
  const float* bh = lstm ? b_hh2 : b_hh1;

  half8 Bx[4];      // x-chunk weights (lstm0 only), k in [0,32)
  half8 Bh[4][2];   // h-chunk weights, k in [32,96)
  float wx[4];      // lstm1: scalar w_ih2 column
  float bias[4];
#pragma unroll
  for (int g = 0; g < 4; ++g) {
    int ncol = 16 * (wave + 4 * g) + col;  // gate index 0..255
    bias[g] = bi[ncol] + bh[ncol];
    if (lstm == 0) {
#pragma unroll
      for (int j = 0; j < 8; ++j) Bx[g][j] = (_Float16)w_ih1[ncol * HG + quad * 8 + j];
    } else {
      wx[g] = w_ih2[ncol];
    }
#pragma unroll
    for (int c = 0; c < 2; ++c) {
#pragma unroll
      for (int j = 0; j < 8; ++j)
        Bh[g][c][j] = (_Float16)w_hh[ncol * HH + c * 32 + quad * 8 + j];
    }
  }

  // Prefetch x for all timesteps
  half8 A0t[TT];
  if (lstm == 0) {
    const _Float16* base = gout + (size_t)(m0 + col) * (TT * HG) + quad * 8;
#pragma unroll
    for (int t = 0; t < TT; ++t) A0t[t] = *(const half8*)(base + t * HG);
  }
  __shared__ float zbuf[TT][16];
  if (lstm == 1 && tid < TT * 16) {
    int t = tid >> 4, s = tid & 15;
    int m = m0 + s;
    int b = m / NN, n = m % NN;
    zbuf[t][s] = zeta[((size_t)b * TT + t) * NN + n];
  }

  // h double buffer: 16 rows x 72 halves (stride 72: 16B-aligned b128 reads)
  __shared__ __align__(16) _Float16 hbuf[2][16 * 72];
  for (int i = tid; i < 16 * 72; i += 256) hbuf[1][i] = (_Float16)0.0f;
  __syncthreads();  // zbuf + hbuf[1] visible to all waves

  float cst[4] = {0.f, 0.f, 0.f, 0.f};
  float hreg[4] = {0.f, 0.f, 0.f, 0.f};

#pragma unroll
  for (int t = 0; t < TT; ++t) {
    const int rp = (t + 1) & 1;  // buffer holding h(t-1)
    if (t > 0) {
#pragma unroll
      for (int r = 0; r < 4; ++r)
        hbuf[rp][(quad * 4 + r) * 72 + 16 * wave + col] = (_Float16)hreg[r];
    }
    // register/read-only work before the barrier
    f32x4 acc[4];
    if (lstm == 0) {
#pragma unroll
      for (int g = 0; g < 4; ++g) {
        f32x4 a; a[0] = bias[g]; a[1] = bias[g]; a[2] = bias[g]; a[3] = bias[g];
        acc[g] = __builtin_amdgcn_mfma_f32_16x16x32_f16(A0t[t], Bx[g], a, 0, 0, 0);
      }
    } else {
#pragma unroll
      for (int g = 0; g < 4; ++g) {
#pragma unroll
        for (int r = 0; r < 4; ++r)
          acc[g][r] = bias[g] + wx[g] * zbuf[t][quad * 4 + r];
      }
    }
    __syncthreads();
    const half8 A1 = *(const half8*)(&hbuf[rp][col * 72 + quad * 8]);
    const half8 A2 = *(const half8*)(&hbuf[rp][col * 72 + 32 + quad * 8]);
#pragma unroll
    for (int g = 0; g < 4; ++g) {
      acc[g] = __builtin_amdgcn_mfma_f32_16x16x32_f16(A1, Bh[g][0], acc[g], 0, 0, 0);
      acc[g] = __builtin_amdgcn_mfma_f32_16x16x32_f16(A2, Bh[g][1], acc[g], 0, 0, 0);
    }
#pragma unroll
    for (int r = 0; r < 4; ++r) {
      float ig = sigm(acc[0][r]);
      float fg = sigm(acc[1][r]);
      float gg = tanhfast(acc[2][r]);
      float og = sigm(acc[3][r]);
      cst[r] = fg * cst[r] + ig * gg;
      hreg[r] = og * tanhfast(cst[r]);
    }
  }
#pragma unroll
  for (int r = 0; r < 4; ++r) {
    int s = quad * 4 + r;
    hout[((size_t)lstm * MM + m0 + s) * HH + 16 * wave + col] = hreg[r];
  }
}

// ---------------- FC + transpose to [B][P][N] (fp32 out) ----------------
__global__ __launch_bounds__(256) void k_fc(const float* __restrict__ hout,
                                            const float* __restrict__ fw,
                                            const float* __restrict__ fb,
                                            float* __restrict__ out) {
  __shared__ float wf[PP * 2 * HH];  // 512
  __shared__ float bf[PP];
  int tid = threadIdx.x;
  wf[tid] = fw[tid];
  wf[tid + 256] = fw[tid + 256];
  if (tid < PP) bf[tid] = fb[tid];
  __syncthreads();
  int m = blockIdx.x * 256 + tid;
  if (m >= MM) return;
  const f32x4* h1 = (const f32x4*)(hout + (size_t)m * HH);
  const f32x4* h2 = (const f32x4*)(hout + (size_t)(MM + m) * HH);
  float acc[PP];
#pragma unroll
  for (int p = 0; p < PP; ++p) acc[p] = bf[p];
#pragma unroll
  for (int k = 0; k < 16; ++k) {
    f32x4 v = h1[k];
#pragma unroll
    for (int p = 0; p < PP; ++p) {
      acc[p] += v[0] * wf[p * 128 + 4 * k] + v[1] * wf[p * 128 + 4 * k + 1] +
                v[2] * wf[p * 128 + 4 * k + 2] + v[3] * wf[p * 128 + 4 * k + 3];
    }
  }
#pragma unroll
  for (int k = 0; k < 16; ++k) {
    f32x4 v = h2[k];
#pragma unroll
    for (int p = 0; p < PP; ++p) {
      acc[p] += v[0] * wf[p * 128 + 64 + 4 * k] + v[1] * wf[p * 128 + 64 + 4 * k + 1] +
                v[2] * wf[p * 128 + 64 + 4 * k + 2] + v[3] * wf[p * 128 + 64 + 4 * k + 3];
    }
  }
  int b = m / NN, n = m % NN;
#pragma unroll
  for (int p = 0; p < PP; ++p)
    out[((size_t)(b * PP + p)) * NN + n] = acc[p];
}

extern "C" void kernel_launch(void* const* d_in, const int* in_sizes, int n_in,
                              void* d_out, int out_size, void* d_ws, size_t ws_size,
                              hipStream_t stream) {
  (void)in_sizes; (void)n_in; (void)out_size; (void)ws_size;
  const float* era5  = (const float*)d_in[0];
  const float* zeta  = (const float*)d_in[1];
  const int*   eidx  = (const int*)d_in[2];
  const float* gcn_w = (const float*)d_in[3];
  const float* gcn_b = (const float*)d_in[4];
  const float* w_ih1 = (const float*)d_in[5];
  const float* w_hh1 = (const float*)d_in[6];
  const float* b_ih1 = (const float*)d_in[7];
  const float* b_hh1 = (const float*)d_in[8];
  const float* w_ih2 = (const float*)d_in[9];
  const float* w_hh2 = (const float*)d_in[10];
  const float* b_ih2 = (const float*)d_in[11];
  const float* b_hh2 = (const float*)d_in[12];
  const float* fc_w  = (const float*)d_in[13];
  const float* fc_b  = (const float*)d_in[14];
  float* out = (float*)d_out;

  // Compact workspace: peak usage < 32 MB.
  char* ws = (char*)d_ws;
  float*     dinv   = (float*)(ws);                    //  40 KB
  int*       cnt    = (int*)(ws + (64 << 10));
  int*       off    = (int*)(ws + (128 << 10));
  int*       fill   = (int*)(ws + (192 << 10));
  int*       csr    = (int*)(ws + (256 << 10));        // 640 KB -> ends at 896 KB
  _Float16*  xw     = (_Float16*)(ws + (1ull << 20));  // [N][24][32] 15.36 MB
  _Float16*  gout   = (_Float16*)(ws + 17301504ull);   // @16.5 MB, 15.36 MB
  float*     hout   = (float*)(ws + (1ull << 20));     // aliases dead xw: 10.24 MB

  hipMemsetAsync(ws + (64 << 10), 0, (192 << 10), stream);  // cnt, off, fill
  k_count<<<EE / 256, 256, 0, stream>>>(eidx, cnt);
  k_scan<<<1, 1024, 0, stream>>>(cnt, off, dinv);
  k_fill<<<EE / 256, 256, 0, stream>>>(eidx, off, fill, csr);
  k_xw<<<(BT * NN * HG) / 256, 256, 0, stream>>>(era5, gcn_w, xw);
  k_gather<<<(NN + 3) / 4, 256, 0, stream>>>((const uint32_t*)xw, off, csr, dinv,
                                             gcn_b, (uint32_t*)gout);
  k_lstm<<<dim3(MM / 16, 2), 256, 0, stream>>>(gout, zeta, w_ih1, w_hh1, b_ih1, b_hh1,
                                               w_ih2, w_hh2, b_ih2, b_hh2, hout);
  k_fc<<<(MM + 255) / 256, 256, 0, stream>>>(hout, fc_w, fc_b, out);
}

// Round 6
// 244.105 us; speedup vs baseline: 1.7280x; 1.0608x over previous
//
#include <hip/hip_runtime.h>
#include <hip/hip_bf16.h>
#include <stdint.h>

// Problem constants (fixed by setup_inputs)
#define NN 10000
#define EE 160000
#define BB 2
#define TT 12
#define FF 16
#define HG 32
#define HH 64
#define PP 4
#define BT (BB*TT)   // 24
#define MM (BB*NN)   // 20000
#define L2E 1.4426950408889634f

typedef _Float16 half8 __attribute__((ext_vector_type(8)));
typedef _Float16 h2 __attribute__((ext_vector_type(2)));
typedef float f32x4 __attribute__((ext_vector_type(4)));

union UP { uint32_t u; h2 h; };

// a pre-scaled by log2(e): sigmoid(x) = rcp(1 + exp2(-L*x))
__device__ __forceinline__ float sigm2(float a) {
  return __builtin_amdgcn_rcpf(1.0f + __builtin_amdgcn_exp2f(-a));
}
// a pre-scaled by 2*log2(e): tanh(x) = 1 - 2*rcp(1 + exp2(2L*x))
__device__ __forceinline__ float tanh2(float a) {
  return fmaf(-2.0f, __builtin_amdgcn_rcpf(1.0f + __builtin_amdgcn_exp2f(a)), 1.0f);
}

// ---------------- GCN: degree histogram ----------------
__global__ void k_count(const int* __restrict__ eidx, int* __restrict__ cnt) {
  int e = blockIdx.x * 256 + threadIdx.x;
  if (e < EE) atomicAdd(&cnt[eidx[EE + e]], 1);
}

// single-block scan: off (exclusive), fill=off copy, dinv = rsqrt(deg+1)
__global__ void k_scan(const int* __restrict__ cnt, int* __restrict__ off,
                       int* __restrict__ fill, float* __restrict__ dinv) {
  __shared__ int partial[1024];
  int tid = threadIdx.x;
  const int CH = 10;
  int base = tid * CH;
  int s = 0;
  for (int i = 0; i < CH; ++i) {
    int idx = base + i;
    if (idx < NN) s += cnt[idx];
  }
  partial[tid] = s;
  __syncthreads();
  for (int d = 1; d < 1024; d <<= 1) {
    int v = (tid >= d) ? partial[tid - d] : 0;
    __syncthreads();
    partial[tid] += v;
    __syncthreads();
  }
  int run = (tid == 0) ? 0 : partial[tid - 1];
  for (int i = 0; i < CH; ++i) {
    int idx = base + i;
    if (idx < NN) {
      off[idx] = run;
      fill[idx] = run;
      int cv = cnt[idx];
      run += cv;
      dinv[idx] = rsqrtf((float)cv + 1.0f);
    }
  }
  if (tid == 1023) off[NN] = run;  // == EE
}

__global__ void k_fill(const int* __restrict__ eidx, int* __restrict__ fill,
                       int* __restrict__ csr) {
  int e = blockIdx.x * 256 + threadIdx.x;
  if (e < EE) {
    int d = eidx[EE + e];
    int pos = atomicAdd(&fill[d], 1);  // fill pre-inited to off[d]
    csr[pos] = eidx[e];
  }
}

// ------- xw = era5 @ gcn_w, layout [N][BT][HG] fp16, coalesced writes -------
__global__ __launch_bounds__(256) void k_xw(const float* __restrict__ era5,
                                            const float* __restrict__ gw,
                                            _Float16* __restrict__ xw) {
  __shared__ float wsm[FF * HG];
  int tid = threadIdx.x;
  wsm[tid] = gw[tid];
  wsm[tid + 256] = gw[tid + 256];
  __syncthreads();
  int idx = blockIdx.x * 256 + tid;       // idx = (n*BT + bt)*HG + c  (write-major)
  int c = idx & 31;
  int rest = idx >> 5;
  int bt = rest % BT;
  int n = rest / BT;
  const float* xr = era5 + ((size_t)bt * NN + n) * FF;
  float acc = 0.f;
#pragma unroll
  for (int f = 0; f < FF; ++f) acc += xr[f] * wsm[f * HG + c];
  xw[idx] = (_Float16)acc;
}

// -------- GCN aggregate: ONE WAVE PER DST, cooperative row gather --------
__global__ __launch_bounds__(256) void k_gather(const uint32_t* __restrict__ xw,
                                                const int* __restrict__ off,
                                                const int* __restrict__ csr,
                                                const float* __restrict__ dinv,
                                                const float* __restrict__ gb,
                                                uint32_t* __restrict__ gout) {
  const int dst = (blockIdx.x * 256 + threadIdx.x) >> 6;
  const int lane = threadIdx.x & 63;
  if (dst >= NN) return;
  const int s0 = off[dst], s1 = off[dst + 1];
  const int cnt = s1 - s0;

  float accs[12];
#pragma unroll
  for (int i = 0; i < 12; ++i) accs[i] = 0.f;

  for (int base = 0; base < cnt; base += 64) {
    int mine = base + lane;
    int sv = 0; float dvv = 0.f;
    if (mine < cnt) { sv = csr[s0 + mine]; dvv = dinv[sv]; }
    int lim = min(64, cnt - base);
    for (int j = 0; j < lim; ++j) {
      int sj = __shfl(sv, j);
      float dj = __shfl(dvv, j);
      const uint32_t* row = xw + (size_t)sj * 384;
#pragma unroll
      for (int k = 0; k < 3; ++k) {
        uint2 d = *(const uint2*)(row + 2 * (lane + 64 * k));
        UP a, b; a.u = d.x; b.u = d.y;
        accs[4 * k + 0] += (float)a.h[0] * dj;
        accs[4 * k + 1] += (float)a.h[1] * dj;
        accs[4 * k + 2] += (float)b.h[0] * dj;
        accs[4 * k + 3] += (float)b.h[1] * dj;
      }
    }
  }
  const float ddst = dinv[dst];
  const uint32_t* srow = xw + (size_t)dst * 384;
  const f32x4 gb4 = *(const f32x4*)(gb + ((4 * lane) & 31));
#pragma unroll
  for (int k = 0; k < 3; ++k) {
    uint2 d = *(const uint2*)(srow + 2 * (lane + 64 * k));
    UP a, b; a.u = d.x; b.u = d.y;
    accs[4 * k + 0] = (accs[4 * k + 0] + (float)a.h[0] * ddst) * ddst + gb4[0];
    accs[4 * k + 1] = (accs[4 * k + 1] + (float)a.h[1] * ddst) * ddst + gb4[1];
    accs[4 * k + 2] = (accs[4 * k + 2] + (float)b.h[0] * ddst) * ddst + gb4[2];
    accs[4 * k + 3] = (accs[4 * k + 3] + (float)b.h[1] * ddst) * ddst + gb4[3];
  }
#pragma unroll
  for (int k = 0; k < 3; ++k) {
    int v0 = 256 * k + 4 * lane;
    int bb = (v0 >= 384) ? 1 : 0;
    UP a, b;
    a.h[0] = (_Float16)accs[4 * k + 0]; a.h[1] = (_Float16)accs[4 * k + 1];
    b.h[0] = (_Float16)accs[4 * k + 2]; b.h[1] = (_Float16)accs[4 * k + 3];
    uint2 d; d.x = a.u; d.y = b.u;
    *(uint2*)(gout + ((size_t)(bb * NN + dst)) * 192 + ((v0 - 384 * bb) >> 1)) = d;
  }
}

// -------- fused dual LSTM + FC (fp16 MFMA, fp32 state, log2e-folded) --------
// Block: 256 thr, 16 sequences, BOTH LSTMs + final FC. Wave w owns hidden
// units [16w,16w+16) x gates {w,w+4,w+8,w+12} for each LSTM. h exchanged via
// per-LSTM double-buffered LDS; one barrier per timestep. t=0 specialized
// (h=0 -> skip h-MFMAs and hbuf init). Weights pre-scaled by log2e (2*log2e
// for the g gate) so activations use raw v_exp/v_rcp with no extra muls.
__global__ __launch_bounds__(256) void k_lstmfc(
    const _Float16* __restrict__ gout, const float* __restrict__ zeta,
    const float* __restrict__ w_ih1, const float* __restrict__ w_hh1,
    const float* __restrict__ b_ih1, const float* __restrict__ b_hh1,
    const float* __restrict__ w_ih2, const float* __restrict__ w_hh2,
    const float* __restrict__ b_ih2, const float* __restrict__ b_hh2,
    const float* __restrict__ fc_w, const float* __restrict__ fc_b,
    float* __restrict__ out) {
  const int m0 = blockIdx.x * 16;
  const int b = (m0 >= NN) ? 1 : 0;
  const int n0 = m0 - b * NN;
  const int tid = threadIdx.x;
  const int wave = tid >> 6;
  const int lane = tid & 63;
  const int col = lane & 15;   // seq for A-read; unit-in-tile for D
  const int quad = lane >> 4;

  half8 Bx[4];        // lstm1 x weights, k in [0,32)
  half8 Bh1[4][2];    // lstm1 h weights
  half8 Bh2[4][2];    // lstm2 h weights
  float bias1[4], bias2[4], wx[4];
#pragma unroll
  for (int g = 0; g < 4; ++g) {
    const float sc = (g == 2) ? 2.0f * L2E : L2E;
    int ncol = 16 * (wave + 4 * g) + col;
    bias1[g] = (b_ih1[ncol] + b_hh1[ncol]) * sc;
    bias2[g] = (b_ih2[ncol] + b_hh2[ncol]) * sc;
    wx[g] = w_ih2[ncol] * sc;
#pragma unroll
    for (int j = 0; j < 8; ++j)
      Bx[g][j] = (_Float16)(w_ih1[ncol * HG + quad * 8 + j] * sc);
#pragma unroll
    for (int c2 = 0; c2 < 2; ++c2) {
#pragma unroll
      for (int j = 0; j < 8; ++j) {
        Bh1[g][c2][j] = (_Float16)(w_hh1[ncol * HH + c2 * 32 + quad * 8 + j] * sc);
        Bh2[g][c2][j] = (_Float16)(w_hh2[ncol * HH + c2 * 32 + quad * 8 + j] * sc);
      }
    }
  }

  __shared__ float zbuf[TT][16];
  if (tid < TT * 16) {
    int t = tid >> 4, s = tid & 15;
    zbuf[t][s] = zeta[((size_t)b * TT + t) * NN + n0 + s];
  }
  __shared__ __align__(16) _Float16 hb1[2][16 * 72];
  __shared__ __align__(16) _Float16 hb2[2][16 * 72];
  __shared__ float fcb[16][132];

  const _Float16* gbase = gout + (size_t)(m0 + col) * (TT * HG) + quad * 8;
  half8 A0 = *(const half8*)(gbase);  // t=0

  float c1[4] = {0.f, 0.f, 0.f, 0.f}, c2v[4] = {0.f, 0.f, 0.f, 0.f};
  float h1f[4], h2f[4];

  __syncthreads();  // zbuf visible

#pragma unroll
  for (int t = 0; t < TT; ++t) {
    const int p = t & 1;
    if (t > 0) {
#pragma unroll
      for (int r = 0; r < 4; ++r) {
        int a = (quad * 4 + r) * 72 + 16 * wave + col;
        hb1[p][a] = (_Float16)h1f[r];
        hb2[p][a] = (_Float16)h2f[r];
      }
    }
    f32x4 a1[4], a2[4];
#pragma unroll
    for (int g = 0; g < 4; ++g) {
      f32x4 ai; ai[0] = bias1[g]; ai[1] = bias1[g]; ai[2] = bias1[g]; ai[3] = bias1[g];
      a1[g] = __builtin_amdgcn_mfma_f32_16x16x32_f16(A0, Bx[g], ai, 0, 0, 0);
#pragma unroll
      for (int r = 0; r < 4; ++r)
        a2[g][r] = fmaf(wx[g], zbuf[t][quad * 4 + r], bias2[g]);
    }
    if (t < TT - 1) A0 = *(const half8*)(gbase + (t + 1) * HG);  // prefetch
    if (t > 0) {
      __syncthreads();
      const half8 A11 = *(const half8*)(&hb1[p][col * 72 + quad * 8]);
      const half8 A21 = *(const half8*)(&hb1[p][col * 72 + 32 + quad * 8]);
      const half8 A12 = *(const half8*)(&hb2[p][col * 72 + quad * 8]);
      const half8 A22 = *(const half8*)(&hb2[p][col * 72 + 32 + quad * 8]);
#pragma unroll
      for (int g = 0; g < 4; ++g) {
        a1[g] = __builtin_amdgcn_mfma_f32_16x16x32_f16(A11, Bh1[g][0], a1[g], 0, 0, 0);
        a1[g] = __builtin_amdgcn_mfma_f32_16x16x32_f16(A21, Bh1[g][1], a1[g], 0, 0, 0);
        a2[g] = __builtin_amdgcn_mfma_f32_16x16x32_f16(A12, Bh2[g][0], a2[g], 0, 0, 0);
        a2[g] = __builtin_amdgcn_mfma_f32_16x16x32_f16(A22, Bh2[g][1], a2[g], 0, 0, 0);
      }
    }
#pragma unroll
    for (int r = 0; r < 4; ++r) {
      float i1 = sigm2(a1[0][r]), f1 = sigm2(a1[1][r]);
      float g1 = tanh2(a1[2][r]), o1 = sigm2(a1[3][r]);
      c1[r] = fmaf(f1, c1[r], i1 * g1);
      h1f[r] = o1 * tanh2(c1[r] * (2.0f * L2E));
      float i2 = sigm2(a2[0][r]), f2 = sigm2(a2[1][r]);
      float g2 = tanh2(a2[2][r]), o2 = sigm2(a2[3][r]);
      c2v[r] = fmaf(f2, c2v[r], i2 * g2);
      h2f[r] = o2 * tanh2(c2v[r] * (2.0f * L2E));
    }
  }
  // FC epilogue: combined[seq][128] = [h1 | h2] in fp32
#pragma unroll
  for (int r = 0; r < 4; ++r) {
    fcb[quad * 4 + r][16 * wave + col] = h1f[r];
    fcb[quad * 4 + r][64 + 16 * wave + col] = h2f[r];
  }
  __syncthreads();
  if (tid < 64) {
    int pp = tid >> 4, s = tid & 15;
    const f32x4* wr = (const f32x4*)(fc_w + pp * 128);
    const float* hv = fcb[s];
    float acc = fc_b[pp];
#pragma unroll
    for (int k = 0; k < 32; ++k) {
      f32x4 w4 = wr[k];
      acc += w4[0] * hv[4 * k] + w4[1] * hv[4 * k + 1] +
             w4[2] * hv[4 * k + 2] + w4[3] * hv[4 * k + 3];
    }
    out[((size_t)(b * PP + pp)) * NN + n0 + s] = acc;
  }
}

extern "C" void kernel_launch(void* const* d_in, const int* in_sizes, int n_in,
                              void* d_out, int out_size, void* d_ws, size_t ws_size,
                              hipStream_t stream) {
  (void)in_sizes; (void)n_in; (void)out_size; (void)ws_size;
  const float* era5  = (const float*)d_in[0];
  const float* zeta  = (const float*)d_in[1];
  const int*   eidx  = (const int*)d_in[2];
  const float* gcn_w = (const float*)d_in[3];
  const float* gcn_b = (const float*)d_in[4];
  const float* w_ih1 = (const float*)d_in[5];
  const float* w_hh1 = (const float*)d_in[6];
  const float* b_ih1 = (const float*)d_in[7];
  const float* b_hh1 = (const float*)d_in[8];
  const float* w_ih2 = (const float*)d_in[9];
  const float* w_hh2 = (const float*)d_in[10];
  const float* b_ih2 = (const float*)d_in[11];
  const float* b_hh2 = (const float*)d_in[12];
  const float* fc_w  = (const float*)d_in[13];
  const float* fc_b  = (const float*)d_in[14];
  float* out = (float*)d_out;

  char* ws = (char*)d_ws;
  float*     dinv   = (float*)(ws);                    //  40 KB
  int*       cnt    = (int*)(ws + (64 << 10));
  int*       off    = (int*)(ws + (128 << 10));
  int*       fill   = (int*)(ws + (192 << 10));
  int*       csr    = (int*)(ws + (256 << 10));        // 640 KB -> ends at 896 KB
  _Float16*  xw     = (_Float16*)(ws + (1ull << 20));  // [N][24][32] 15.36 MB
  _Float16*  gout   = (_Float16*)(ws + 17301504ull);   // @16.5 MB, 15.36 MB

  hipMemsetAsync(cnt, 0, NN * sizeof(int), stream);    // only cnt needs zeroing
  k_count<<<EE / 256, 256, 0, stream>>>(eidx, cnt);
  k_scan<<<1, 1024, 0, stream>>>(cnt, off, fill, dinv);
  k_fill<<<EE / 256, 256, 0, stream>>>(eidx, fill, csr);
  k_xw<<<(BT * NN * HG) / 256, 256, 0, stream>>>(era5, gcn_w, xw);
  k_gather<<<(NN + 3) / 4, 256, 0, stream>>>((const uint32_t*)xw, off, csr, dinv,
                                             gcn_b, (uint32_t*)gout);
  k_lstmfc<<<MM / 16, 256, 0, stream>>>(gout, zeta, w_ih1, w_hh1, b_ih1, b_hh1,
                                        w_ih2, w_hh2, b_ih2, b_hh2, fc_w, fc_b, out);
}

// Round 7
// 191.030 us; speedup vs baseline: 2.2082x; 1.2778x over previous
//
#include <hip/hip_runtime.h>
#include <hip/hip_bf16.h>
#include <stdint.h>

// Problem constants (fixed by setup_inputs)
#define NN 10000
#define EE 160000
#define BB 2
#define TT 12
#define FF 16
#define HG 32
#define HH 64
#define PP 4
#define BT (BB*TT)   // 24
#define MM (BB*NN)   // 20000
#define CAP 96       // fixed CSR capacity/node: deg ~ Binom(160k,1e-4), 20 sigma
#define L2E 1.4426950408889634f

typedef _Float16 half8 __attribute__((ext_vector_type(8)));
typedef _Float16 h2 __attribute__((ext_vector_type(2)));
typedef float f32x4 __attribute__((ext_vector_type(4)));

union UP { uint32_t u; h2 h; };

// a pre-scaled by log2(e): sigmoid(x) = rcp(1 + exp2(-L*x))
__device__ __forceinline__ float sigm2(float a) {
  return __builtin_amdgcn_rcpf(1.0f + __builtin_amdgcn_exp2f(-a));
}
// a pre-scaled by 2*log2(e): tanh(x) = 1 - 2*rcp(1 + exp2(2L*x))
__device__ __forceinline__ float tanh2(float a) {
  return fmaf(-2.0f, __builtin_amdgcn_rcpf(1.0f + __builtin_amdgcn_exp2f(a)), 1.0f);
}

// ---- CSR build, one pass: fixed-capacity rows, count via atomic return ----
__global__ void k_fill(const int* __restrict__ eidx, int* __restrict__ cnt,
                       int* __restrict__ csr) {
  int e = blockIdx.x * 256 + threadIdx.x;
  if (e < EE) {
    int d = eidx[EE + e];
    int pos = atomicAdd(&cnt[d], 1);
    if (pos < CAP) csr[d * CAP + pos] = eidx[e];
  }
}

// ---- transpose era5 [BT][N][F] fp32 -> xt [N][BT][F] fp16 (dword writes) ----
__global__ __launch_bounds__(256) void k_prep(const float* __restrict__ era5,
                                              uint32_t* __restrict__ xt) {
  int D = blockIdx.x * 256 + threadIdx.x;   // dword index, NN*BT*8 total
  int f2 = D & 7;
  int bt = (D >> 3) % BT;
  int n = D / (8 * BT);
  const float* src = era5 + ((size_t)bt * NN + n) * FF + f2 * 2;
  UP u; u.h[0] = (_Float16)src[0]; u.h[1] = (_Float16)src[1];
  xt[D] = u.u;
}

// ---- GCN aggregate on RAW features (768B/row) + fused W-apply ----
// 4 dst/block (wave per dst). Lane owns 3 dwords (6 halfwords) of the
// [BT][F] row. After aggregation: agg -> LDS, block applies W (16->32) and
// writes gout [B*N][T][HG] fp16 coalesced.
__global__ __launch_bounds__(256) void k_gather(const uint32_t* __restrict__ xt,
                                                const int* __restrict__ csr,
                                                const int* __restrict__ cnt,
                                                const float* __restrict__ gw,
                                                const float* __restrict__ gb,
                                                uint32_t* __restrict__ gout) {
  __shared__ float wsm[FF * HG];     // 2 KB
  __shared__ float gbs[HG];
  __shared__ float agg[4][BT][FF];   // 6 KB
  const int tid = threadIdx.x;
  wsm[tid] = gw[tid];
  wsm[tid + 256] = gw[tid + 256];
  if (tid < HG) gbs[tid] = gb[tid];

  const int dloc = tid >> 6, lane = tid & 63;
  const int dst = blockIdx.x * 4 + dloc;
  const int cdst = min(cnt[dst], CAP);
  const float dinv_d = rsqrtf((float)cdst + 1.0f);

  float acc[6];
#pragma unroll
  for (int i = 0; i < 6; ++i) acc[i] = 0.f;

  for (int base = 0; base < cdst; base += 64) {
    int mine = base + lane;
    int sv = 0; float dvv = 0.f;
    if (mine < cdst) {
      sv = csr[dst * CAP + mine];
      dvv = rsqrtf((float)cnt[sv] + 1.0f);
    }
    int lim = min(64, cdst - base);
    for (int j = 0; j < lim; ++j) {
      int sj = __shfl(sv, j);
      float dj = __shfl(dvv, j);
      const uint32_t* row = xt + (size_t)sj * 192;
#pragma unroll
      for (int k = 0; k < 3; ++k) {
        UP u; u.u = row[lane + 64 * k];
        acc[2 * k] += (float)u.h[0] * dj;
        acc[2 * k + 1] += (float)u.h[1] * dj;
      }
    }
  }
  // self-loop + normalize, stage to LDS
  const uint32_t* srow = xt + (size_t)dst * 192;
#pragma unroll
  for (int k = 0; k < 3; ++k) {
    UP u; u.u = srow[lane + 64 * k];
    int d0 = lane + 64 * k;
    int bt = d0 >> 3, f = (d0 & 7) * 2;
    agg[dloc][bt][f]     = (acc[2 * k]     + (float)u.h[0] * dinv_d) * dinv_d;
    agg[dloc][bt][f + 1] = (acc[2 * k + 1] + (float)u.h[1] * dinv_d) * dinv_d;
  }
  __syncthreads();
  // W-apply: thread writes dwords {lane, lane+64, lane+128} of both b-rows
#pragma unroll
  for (int k = 0; k < 3; ++k) {
    int d0 = lane + 64 * k;
    int t = d0 >> 4, c0 = (d0 & 15) * 2;
#pragma unroll
    for (int b = 0; b < 2; ++b) {
      const float* av = agg[dloc][b * TT + t];
      float v0 = gbs[c0], v1 = gbs[c0 + 1];
#pragma unroll
      for (int f = 0; f < FF; ++f) {
        v0 = fmaf(av[f], wsm[f * HG + c0], v0);
        v1 = fmaf(av[f], wsm[f * HG + c0 + 1], v1);
      }
      UP u; u.h[0] = (_Float16)v0; u.h[1] = (_Float16)v1;
      gout[((size_t)(b * NN + dst)) * 192 + d0] = u.u;
    }
  }
}

// -------- fused dual LSTM + FC (fp16 MFMA, fp32 state, log2e-folded) --------
__global__ __launch_bounds__(256) void k_lstmfc(
    const _Float16* __restrict__ gout, const float* __restrict__ zeta,
    const float* __restrict__ w_ih1, const float* __restrict__ w_hh1,
    const float* __restrict__ b_ih1, const float* __restrict__ b_hh1,
    const float* __restrict__ w_ih2, const float* __restrict__ w_hh2,
    const float* __restrict__ b_ih2, const float* __restrict__ b_hh2,
    const float* __restrict__ fc_w, const float* __restrict__ fc_b,
    float* __restrict__ out) {
  const int m0 = blockIdx.x * 16;
  const int b = (m0 >= NN) ? 1 : 0;
  const int n0 = m0 - b * NN;
  const int tid = threadIdx.x;
  const int wave = tid >> 6;
  const int lane = tid & 63;
  const int col = lane & 15;
  const int quad = lane >> 4;

  half8 Bx[4];
  half8 Bh1[4][2];
  half8 Bh2[4][2];
  float bias1[4], bias2[4], wx[4];
#pragma unroll
  for (int g = 0; g < 4; ++g) {
    const float sc = (g == 2) ? 2.0f * L2E : L2E;
    int ncol = 16 * (wave + 4 * g) + col;
    bias1[g] = (b_ih1[ncol] + b_hh1[ncol]) * sc;
    bias2[g] = (b_ih2[ncol] + b_hh2[ncol]) * sc;
    wx[g] = w_ih2[ncol] * sc;
#pragma unroll
    for (int j = 0; j < 8; ++j)
      Bx[g][j] = (_Float16)(w_ih1[ncol * HG + quad * 8 + j] * sc);
#pragma unroll
    for (int c2 = 0; c2 < 2; ++c2) {
#pragma unroll
      for (int j = 0; j < 8; ++j) {
        Bh1[g][c2][j] = (_Float16)(w_hh1[ncol * HH + c2 * 32 + quad * 8 + j] * sc);
        Bh2[g][c2][j] = (_Float16)(w_hh2[ncol * HH + c2 * 32 + quad * 8 + j] * sc);
      }
    }
  }

  __shared__ float zbuf[TT][16];
  if (tid < TT * 16) {
    int t = tid >> 4, s = tid & 15;
    zbuf[t][s] = zeta[((size_t)b * TT + t) * NN + n0 + s];
  }
  __shared__ __align__(16) _Float16 hb1[2][16 * 72];
  __shared__ __align__(16) _Float16 hb2[2][16 * 72];
  __shared__ float fcb[16][132];

  const _Float16* gbase = gout + (size_t)(m0 + col) * (TT * HG) + quad * 8;
  half8 A0 = *(const half8*)(gbase);

  float c1[4] = {0.f, 0.f, 0.f, 0.f}, c2v[4] = {0.f, 0.f, 0.f, 0.f};
  float h1f[4], h2f[4];

  __syncthreads();

#pragma unroll
  for (int t = 0; t < TT; ++t) {
    const int p = t & 1;
    if (t > 0) {
#pragma unroll
      for (int r = 0; r < 4; ++r) {
        int a = (quad * 4 + r) * 72 + 16 * wave + col;
        hb1[p][a] = (_Float16)h1f[r];
        hb2[p][a] = (_Float16)h2f[r];
      }
    }
    f32x4 a1[4], a2[4];
#pragma unroll
    for (int g = 0; g < 4; ++g) {
      f32x4 ai; ai[0] = bias1[g]; ai[1] = bias1[g]; ai[2] = bias1[g]; ai[3] = bias1[g];
      a1[g] = __builtin_amdgcn_mfma_f32_16x16x32_f16(A0, Bx[g], ai, 0, 0, 0);
#pragma unroll
      for (int r = 0; r < 4; ++r)
        a2[g][r] = fmaf(wx[g], zbuf[t][quad * 4 + r], bias2[g]);
    }
    if (t < TT - 1) A0 = *(const half8*)(gbase + (t + 1) * HG);
    if (t > 0) {
      __syncthreads();
      const half8 A11 = *(const half8*)(&hb1[p][col * 72 + quad * 8]);
      const half8 A21 = *(const half8*)(&hb1[p][col * 72 + 32 + quad * 8]);
      const half8 A12 = *(const half8*)(&hb2[p][col * 72 + quad * 8]);
      const half8 A22 = *(const half8*)(&hb2[p][col * 72 + 32 + quad * 8]);
#pragma unroll
      for (int g = 0; g < 4; ++g) {
        a1[g] = __builtin_amdgcn_mfma_f32_16x16x32_f16(A11, Bh1[g][0], a1[g], 0, 0, 0);
        a1[g] = __builtin_amdgcn_mfma_f32_16x16x32_f16(A21, Bh1[g][1], a1[g], 0, 0, 0);
        a2[g] = __builtin_amdgcn_mfma_f32_16x16x32_f16(A12, Bh2[g][0], a2[g], 0, 0, 0);
        a2[g] = __builtin_amdgcn_mfma_f32_16x16x32_f16(A22, Bh2[g][1], a2[g], 0, 0, 0);
      }
    }
#pragma unroll
    for (int r = 0; r < 4; ++r) {
      float i1 = sigm2(a1[0][r]), f1 = sigm2(a1[1][r]);
      float g1 = tanh2(a1[2][r]), o1 = sigm2(a1[3][r]);
      c1[r] = fmaf(f1, c1[r], i1 * g1);
      h1f[r] = o1 * tanh2(c1[r] * (2.0f * L2E));
      float i2 = sigm2(a2[0][r]), f2 = sigm2(a2[1][r]);
      float g2 = tanh2(a2[2][r]), o2 = sigm2(a2[3][r]);
      c2v[r] = fmaf(f2, c2v[r], i2 * g2);
      h2f[r] = o2 * tanh2(c2v[r] * (2.0f * L2E));
    }
  }
#pragma unroll
  for (int r = 0; r < 4; ++r) {
    fcb[quad * 4 + r][16 * wave + col] = h1f[r];
    fcb[quad * 4 + r][64 + 16 * wave + col] = h2f[r];
  }
  __syncthreads();
  if (tid < 64) {
    int pp = tid >> 4, s = tid & 15;
    const f32x4* wr = (const f32x4*)(fc_w + pp * 128);
    const float* hv = fcb[s];
    float acc = fc_b[pp];
#pragma unroll
    for (int k = 0; k < 32; ++k) {
      f32x4 w4 = wr[k];
      acc += w4[0] * hv[4 * k] + w4[1] * hv[4 * k + 1] +
             w4[2] * hv[4 * k + 2] + w4[3] * hv[4 * k + 3];
    }
    out[((size_t)(b * PP + pp)) * NN + n0 + s] = acc;
  }
}

extern "C" void kernel_launch(void* const* d_in, const int* in_sizes, int n_in,
                              void* d_out, int out_size, void* d_ws, size_t ws_size,
                              hipStream_t stream) {
  (void)in_sizes; (void)n_in; (void)out_size; (void)ws_size;
  const float* era5  = (const float*)d_in[0];
  const float* zeta  = (const float*)d_in[1];
  const int*   eidx  = (const int*)d_in[2];
  const float* gcn_w = (const float*)d_in[3];
  const float* gcn_b = (const float*)d_in[4];
  const float* w_ih1 = (const float*)d_in[5];
  const float* w_hh1 = (const float*)d_in[6];
  const float* b_ih1 = (const float*)d_in[7];
  const float* b_hh1 = (const float*)d_in[8];
  const float* w_ih2 = (const float*)d_in[9];
  const float* w_hh2 = (const float*)d_in[10];
  const float* b_ih2 = (const float*)d_in[11];
  const float* b_hh2 = (const float*)d_in[12];
  const float* fc_w  = (const float*)d_in[13];
  const float* fc_b  = (const float*)d_in[14];
  float* out = (float*)d_out;

  char* ws = (char*)d_ws;
  int*      cnt  = (int*)(ws);                        // 40 KB
  int*      csr  = (int*)(ws + (64 << 10));           // 10000*96*4 = 3.84 MB
  uint32_t* xt   = (uint32_t*)(ws + (4ull << 20));    // [N][BT][F] fp16, 7.68 MB
  _Float16* gout = (_Float16*)(ws + (12ull << 20));   // [B*N][T][HG] fp16, 15.36 MB

  hipMemsetAsync(cnt, 0, NN * sizeof(int), stream);
  k_fill<<<EE / 256, 256, 0, stream>>>(eidx, cnt, csr);
  k_prep<<<(NN * BT * 8) / 256, 256, 0, stream>>>(era5, xt);
  k_gather<<<NN / 4, 256, 0, stream>>>(xt, csr, cnt, gcn_w, gcn_b, (uint32_t*)gout);
  k_lstmfc<<<MM / 16, 256, 0, stream>>>(gout, zeta, w_ih1, w_hh1, b_ih1, b_hh1,
                                        w_ih2, w_hh2, b_ih2, b_hh2, fc_w, fc_b, out);
}